// Round 6
// baseline (1936.666 us; speedup 1.0000x reference)
//
#include <hip/hip_runtime.h>
#include <math.h>

#define NB 256
#define NL 50
#define NK 100
#define NHID 64

// ---- main fused kernel: one block per (b,l) ----
// __launch_bounds__(128, 2): 2 waves/SIMD target -> VGPR cap ~256, room for
// z2[48]+z1c[32] fully in registers (VGPR=68 + scratch spill was the R1/R5 killer).
__global__ __launch_bounds__(128, 2) void edge_kernel(
    const int* __restrict__ history,
    const float* __restrict__ neighbor,
    const float* __restrict__ item_table,
    const float* __restrict__ Wa, const float* __restrict__ ba,
    const float* __restrict__ W1, const float* __restrict__ b1v,
    const float* __restrict__ W2, const float* __restrict__ b2,
    const float* __restrict__ W3, const float* __restrict__ b3,
    const float* __restrict__ Wh, const float* __restrict__ bh,
    float* __restrict__ acc_out)   // [NB][64] fp32, pre-zeroed
{
    const int bl  = blockIdx.x;
    const int b   = bl / NL;
    const int tid = threadIdx.x;

    __shared__ float nb_s[NK * 65];   // padded stride 65: conflict-free both axes
    __shared__ float hist_s[64];
    __shared__ float base1_s[96];
    __shared__ float red_s[128];
    __shared__ float agg_s[64];

    const int hid = history[bl];
    if (tid < 64) hist_s[tid] = item_table[(size_t)hid * NHID + tid];

    // stage neighbor tile [100][64] -> LDS (coalesced global reads)
    const float* nbg = neighbor + (size_t)bl * (NK * NHID);
    for (int f = tid; f < NK * NHID; f += 128)
        nb_s[(f >> 6) * 65 + (f & 63)] = nbg[f];
    __syncthreads();

    // base1[j] = ba[j] + sum_i hist[i] * Wa[i][j]   (hist part shared by all K edges)
    if (tid < 96) {
        float a = ba[tid];
        #pragma unroll 4
        for (int i = 0; i < 64; ++i)
            a += hist_s[i] * Wa[i * 96 + tid];
        base1_s[tid] = a;
    }
    __syncthreads();

    const bool valid = tid < NK;
    const int  e     = valid ? tid : NK - 1;
    const float* nbrow = &nb_s[e * 65];

    // ---- layers 1+2 fused, chunked; ALL private-array indices compile-time ----
    float z2[48];
    #pragma unroll
    for (int m = 0; m < 48; ++m) z2[m] = b1v[m];

    #pragma unroll
    for (int c = 0; c < 3; ++c) {
        float z1c[32];
        #pragma unroll
        for (int j = 0; j < 32; ++j) z1c[j] = base1_s[c * 32 + j];
        #pragma unroll 2
        for (int i = 0; i < 64; ++i) {          // i runtime: only LDS/s_load indexed
            float v = nbrow[i];
            const float* wr = &Wa[(64 + i) * 96 + c * 32];  // uniform -> s_load
            #pragma unroll
            for (int j = 0; j < 32; ++j) z1c[j] += v * wr[j];
        }
        #pragma unroll
        for (int j = 0; j < 32; ++j) {          // fully unrolled: z1c stays in VGPRs
            float z = fmaxf(z1c[j], 0.f);
            const float* w1r = &W1[(c * 32 + j) * 48];      // uniform, contiguous
            #pragma unroll
            for (int m = 0; m < 48; ++m) z2[m] += z * w1r[m];
        }
    }

    // ---- layer 3 + logit (fully unrolled: z2/z3 stay in VGPRs) ----
    float z3[16];
    #pragma unroll
    for (int m2 = 0; m2 < 16; ++m2) z3[m2] = b2[m2];
    #pragma unroll
    for (int m = 0; m < 48; ++m) {
        float h2m = fmaxf(z2[m], 0.f);
        const float* w2r = &W2[m * 16];
        #pragma unroll
        for (int m2 = 0; m2 < 16; ++m2) z3[m2] += h2m * w2r[m2];
    }
    float lg = b3[0];
    #pragma unroll
    for (int m2 = 0; m2 < 16; ++m2) lg += fmaxf(z3[m2], 0.f) * W3[m2];

    // ---- softmax over the 100 edges ----
    float logit = valid ? lg : -1e30f;
    red_s[tid] = logit;
    __syncthreads();
    for (int s = 64; s > 0; s >>= 1) {
        if (tid < s) red_s[tid] = fmaxf(red_s[tid], red_s[tid + s]);
        __syncthreads();
    }
    float mx = red_s[0];
    __syncthreads();
    float p = valid ? __expf(logit - mx) : 0.f;
    red_s[tid] = p;
    __syncthreads();
    for (int s = 64; s > 0; s >>= 1) {
        if (tid < s) red_s[tid] += red_s[tid + s];
        __syncthreads();
    }
    float inv_sum = 1.f / red_s[0];
    __syncthreads();
    red_s[tid] = p * inv_sum;     // red_s now holds softmax weights
    __syncthreads();

    // ---- agg[h] = sum_k w[k] * nb[k][h]  (exact fp32 from LDS) ----
    if (tid < 64) {
        float a = 0.f;
        for (int k = 0; k < NK; ++k)
            a += red_s[k] * nb_s[k * 65 + tid];
        agg_s[tid] = a;
    }
    __syncthreads();

    // ---- heads: out64[n*16+d] = bh + sum_h agg[h]*Wh[n][h][d]; accumulate over l ----
    if (tid < 64) {
        const int n = tid >> 4, d = tid & 15;
        float hv = bh[tid];
        #pragma unroll 4
        for (int h = 0; h < 64; ++h)
            hv += agg_s[h] * Wh[n * (64 * 16) + h * 16 + d];
        atomicAdd(&acc_out[b * NHID + tid], hv);
    }
}

// ---- final head: combined = [user_emb | agg_mean] -> relu(Wf1) -> sigmoid(Wo) ----
__global__ __launch_bounds__(64) void final_kernel(
    const int* __restrict__ user_ids,
    const float* __restrict__ user_table,
    const float* __restrict__ acc,
    const float* __restrict__ Wf1, const float* __restrict__ bf1,
    const float* __restrict__ Wo,  const float* __restrict__ bo,
    float* __restrict__ out)
{
    const int b = blockIdx.x, h = threadIdx.x;
    __shared__ float ue[64], ag[64];
    const int uid = user_ids[b];
    ue[h] = user_table[(size_t)uid * 64 + h];
    ag[h] = acc[b * 64 + h] * (1.f / 50.f);
    __syncthreads();
    float z = bf1[h];
    #pragma unroll 4
    for (int i = 0; i < 64; ++i) z += ue[i] * Wf1[i * 64 + h];
    #pragma unroll 4
    for (int i = 0; i < 64; ++i) z += ag[i] * Wf1[(64 + i) * 64 + h];
    float t = fmaxf(z, 0.f) * Wo[h];
    #pragma unroll
    for (int off = 32; off > 0; off >>= 1) t += __shfl_down(t, off, 64);
    if (h == 0) out[b] = 1.f / (1.f + __expf(-(t + bo[0])));
}

extern "C" void kernel_launch(void* const* d_in, const int* in_sizes, int n_in,
                              void* d_out, int out_size, void* d_ws, size_t ws_size,
                              hipStream_t stream) {
    const int*   user_ids   = (const int*)d_in[0];
    const int*   history    = (const int*)d_in[2];
    const float* neighbor   = (const float*)d_in[3];
    const float* user_table = (const float*)d_in[4];
    const float* item_table = (const float*)d_in[5];
    const float* Wa  = (const float*)d_in[6];
    const float* ba  = (const float*)d_in[7];
    const float* W1  = (const float*)d_in[8];
    const float* b1  = (const float*)d_in[9];
    const float* W2  = (const float*)d_in[10];
    const float* b2  = (const float*)d_in[11];
    const float* W3  = (const float*)d_in[12];
    const float* b3  = (const float*)d_in[13];
    const float* Wh  = (const float*)d_in[14];
    const float* bh  = (const float*)d_in[15];
    const float* Wf1 = (const float*)d_in[16];
    const float* bf1 = (const float*)d_in[17];
    const float* Wo  = (const float*)d_in[18];
    const float* bo  = (const float*)d_in[19];

    float* acc = (float*)d_ws;                    // NB*64 floats, zeroed each call

    hipMemsetAsync(acc, 0, NB * NHID * sizeof(float), stream);
    edge_kernel<<<NB * NL, 128, 0, stream>>>(history, neighbor, item_table,
        Wa, ba, W1, b1, W2, b2, W3, b3, Wh, bh, acc);
    final_kernel<<<NB, 64, 0, stream>>>(user_ids, user_table, acc, Wf1, bf1, Wo, bo,
                                        (float*)d_out);
}

// Round 7
// 391.725 us; speedup vs baseline: 4.9439x; 4.9439x over previous
//
#include <hip/hip_runtime.h>
#include <hip/hip_bf16.h>
#include <math.h>

#define NB 256
#define NL 50
#define NK 100
#define NHID 64

typedef __attribute__((ext_vector_type(8))) short short8;   // 8 bf16 = 4 VGPR
typedef __attribute__((ext_vector_type(4))) float floatx4;  // C/D frag

__device__ __forceinline__ short f2bf(float f) {
    __hip_bfloat16 h = __float2bfloat16(f);
    return *reinterpret_cast<short*>(&h);
}
__device__ __forceinline__ float bf2f(short s) {
    __hip_bfloat16 h = *reinterpret_cast<__hip_bfloat16*>(&s);
    return __bfloat162float(h);
}

// ---- pack weights into bf16 B-fragment order (lane-contiguous 16B) ----
// B-frag for 16x16x32: lane l holds B[k = kstep*32 + (l>>4)*8 + j][n0 + (l&15)], j=0..7
__global__ __launch_bounds__(256) void pack_kernel(
    const float* __restrict__ Wa, const float* __restrict__ W1,
    const float* __restrict__ W2,
    short* __restrict__ WaP, short* __restrict__ W1P, short* __restrict__ W2P)
{
    int t = threadIdx.x;
    for (int s = t; s < 12 * 64; s += 256) {        // Wa_bot [64,96]: 6 ntiles x 2 ksteps
        int l = s & 63, nt = s >> 6, n = nt >> 1, tk = nt & 1;
        int col = n * 16 + (l & 15);
        for (int j = 0; j < 8; ++j) {
            int k = tk * 32 + ((l >> 4) * 8) + j;
            WaP[s * 8 + j] = f2bf(Wa[(64 + k) * 96 + col]);
        }
    }
    for (int s = t; s < 9 * 64; s += 256) {         // W1 [96,48]: 3 ntiles x 3 ksteps
        int l = s & 63, nt = s >> 6, n = nt / 3, tk = nt % 3;
        int col = n * 16 + (l & 15);
        for (int j = 0; j < 8; ++j) {
            int k = tk * 32 + ((l >> 4) * 8) + j;
            W1P[s * 8 + j] = f2bf(W1[k * 48 + col]);
        }
    }
    for (int s = t; s < 2 * 64; s += 256) {         // W2 [48,16] pad K->64: 1 ntile x 2 ksteps
        int l = s & 63, tk = s >> 6;
        int col = l & 15;
        for (int j = 0; j < 8; ++j) {
            int k = tk * 32 + ((l >> 4) * 8) + j;
            W2P[s * 8 + j] = (k < 48) ? f2bf(W2[k * 16 + col]) : (short)0;
        }
    }
}

// ---- main fused kernel: one 256-thread block (4 waves) per (b,l) ----
__global__ __launch_bounds__(256) void edge_kernel(
    const int* __restrict__ history,
    const float* __restrict__ neighbor,
    const float* __restrict__ item_table,
    const float* __restrict__ Wa, const float* __restrict__ ba,
    const float* __restrict__ b1v, const float* __restrict__ b2,
    const float* __restrict__ W3, const float* __restrict__ b3,
    const float* __restrict__ Wh, const float* __restrict__ bh,
    const short* __restrict__ WaP, const short* __restrict__ W1P,
    const short* __restrict__ W2P,
    float* __restrict__ acc_out)
{
    const int bl  = blockIdx.x;
    const int b   = bl / NL;
    const int tid = threadIdx.x;

    // swizzle: byte ^= ((row&7)<<4) within 128B rows (G4: breaks 16-way conflicts)
    __shared__ __align__(16) short nb_s[112 * 64];      // [112][64] bf16, stride 128B
    __shared__ __align__(16) short z1_s[4][16 * 96];    // per-wave [16][96], stride 192B
    __shared__ __align__(16) short z2_s[4][16 * 64];    // per-wave [16][64], stride 128B (K pad)
    __shared__ float hist_s[64];
    __shared__ float base1_s[96];
    __shared__ float red_s[256];
    __shared__ float agg_s[64];

    const int hid = history[bl];
    if (tid < 64) hist_s[tid] = item_table[(size_t)hid * NHID + tid];

    // stage neighbor tile -> swizzled bf16 LDS
    const float* nbg = neighbor + (size_t)bl * (NK * NHID);
    for (int f = tid; f < NK * NHID; f += 256) {
        int e = f >> 6, h = f & 63;
        int byte = e * 128 + ((2 * h) ^ ((e & 7) << 4));
        *reinterpret_cast<short*>(reinterpret_cast<char*>(nb_s) + byte) = f2bf(nbg[f]);
    }
    __syncthreads();

    // base1[j] = ba[j] + hist . Wa_top[:,j]  (fp32, shared across all 100 edges)
    if (tid < 96) {
        float a = ba[tid];
        #pragma unroll 4
        for (int i = 0; i < 64; ++i) a += hist_s[i] * Wa[i * 96 + tid];
        base1_s[tid] = a;
    }

    const int wv = tid >> 6, ln = tid & 63;
    const int lr = ln & 15;          // A-row / C-col within tile
    const int lg = ln >> 4;          // k-group / C-row-group
    char* z1p = reinterpret_cast<char*>(z1_s[wv]);
    char* z2p = reinterpret_cast<char*>(z2_s[wv]);

    // zero z2 pad cols 48..63 through the same swizzle (wave-private)
    for (int x = ln; x < 16 * 16; x += 64) {
        int r = x >> 4, c = 48 + (x & 15);
        *reinterpret_cast<short*>(z2p + r * 128 + ((2 * c) ^ ((r & 7) << 4))) = 0;
    }
    __syncthreads();   // base1 ready

    const short8* WaPv = reinterpret_cast<const short8*>(WaP);
    const short8* W1Pv = reinterpret_cast<const short8*>(W1P);
    const short8* W2Pv = reinterpret_cast<const short8*>(W2P);
    const float b2c = b2[lr], w3c = W3[lr], b3s = b3[0];

    // each wave owns M-tiles {wv, wv+4}; rows 100..111 are junk -> masked at softmax
    for (int mi = wv; mi < 7; mi += 4) {
        const int er = mi * 16 + lr;
        const char* nbp = reinterpret_cast<const char*>(nb_s) + er * 128;
        const int esw = (er & 7) << 4;
        short8 a0 = *reinterpret_cast<const short8*>(nbp + ((lg * 16 +  0) ^ esw));
        short8 a1 = *reinterpret_cast<const short8*>(nbp + ((lg * 16 + 64) ^ esw));

        // ---- L1: [16,64] x [64,96] -> relu(+base1) -> z1 LDS (bf16) ----
        #pragma unroll
        for (int n = 0; n < 6; ++n) {
            floatx4 acc = {0.f, 0.f, 0.f, 0.f};
            acc = __builtin_amdgcn_mfma_f32_16x16x32_bf16(a0, WaPv[(n * 2 + 0) * 64 + ln], acc, 0, 0, 0);
            acc = __builtin_amdgcn_mfma_f32_16x16x32_bf16(a1, WaPv[(n * 2 + 1) * 64 + ln], acc, 0, 0, 0);
            float base = base1_s[n * 16 + lr];
            #pragma unroll
            for (int i = 0; i < 4; ++i) {
                int r = lg * 4 + i;
                float z = fmaxf(acc[i] + base, 0.f);
                *reinterpret_cast<short*>(z1p + r * 192 + ((2 * (n * 16 + lr)) ^ ((r & 7) << 4))) = f2bf(z);
            }
        }

        // ---- L2: [16,96] x [96,48] -> relu(+b1) -> z2 LDS (bf16, K-padded) ----
        short8 za0 = *reinterpret_cast<const short8*>(z1p + lr * 192 + ((  0 + lg * 16) ^ ((lr & 7) << 4)));
        short8 za1 = *reinterpret_cast<const short8*>(z1p + lr * 192 + (( 64 + lg * 16) ^ ((lr & 7) << 4)));
        short8 za2 = *reinterpret_cast<const short8*>(z1p + lr * 192 + ((128 + lg * 16) ^ ((lr & 7) << 4)));
        #pragma unroll
        for (int n = 0; n < 3; ++n) {
            floatx4 acc = {0.f, 0.f, 0.f, 0.f};
            acc = __builtin_amdgcn_mfma_f32_16x16x32_bf16(za0, W1Pv[(n * 3 + 0) * 64 + ln], acc, 0, 0, 0);
            acc = __builtin_amdgcn_mfma_f32_16x16x32_bf16(za1, W1Pv[(n * 3 + 1) * 64 + ln], acc, 0, 0, 0);
            acc = __builtin_amdgcn_mfma_f32_16x16x32_bf16(za2, W1Pv[(n * 3 + 2) * 64 + ln], acc, 0, 0, 0);
            float bias = b1v[n * 16 + lr];
            #pragma unroll
            for (int i = 0; i < 4; ++i) {
                int r = lg * 4 + i;
                float z = fmaxf(acc[i] + bias, 0.f);
                *reinterpret_cast<short*>(z2p + r * 128 + ((2 * (n * 16 + lr)) ^ ((r & 7) << 4))) = f2bf(z);
            }
        }

        // ---- L3: [16,48(pad64)] x [48,16] -> relu(+b2) . W3 -> logits ----
        short8 zb0 = *reinterpret_cast<const short8*>(z2p + lr * 128 + (( 0 + lg * 16) ^ ((lr & 7) << 4)));
        short8 zb1 = *reinterpret_cast<const short8*>(z2p + lr * 128 + ((64 + lg * 16) ^ ((lr & 7) << 4)));
        floatx4 acc3 = {0.f, 0.f, 0.f, 0.f};
        acc3 = __builtin_amdgcn_mfma_f32_16x16x32_bf16(zb0, W2Pv[ln], acc3, 0, 0, 0);
        acc3 = __builtin_amdgcn_mfma_f32_16x16x32_bf16(zb1, W2Pv[64 + ln], acc3, 0, 0, 0);
        #pragma unroll
        for (int i = 0; i < 4; ++i) {
            float tL = fmaxf(acc3[i] + b2c, 0.f) * w3c;
            tL += __shfl_xor(tL, 1, 64);
            tL += __shfl_xor(tL, 2, 64);
            tL += __shfl_xor(tL, 4, 64);
            tL += __shfl_xor(tL, 8, 64);
            if (lr == 0) red_s[mi * 16 + lg * 4 + i] = tL + b3s;
        }
    }
    __syncthreads();

    // ---- softmax over 100 edges (fp32, block-wide) ----
    float logit = (tid < NK) ? red_s[tid] : -1e30f;
    red_s[tid] = logit;
    __syncthreads();
    for (int s = 128; s > 0; s >>= 1) {
        if (tid < s) red_s[tid] = fmaxf(red_s[tid], red_s[tid + s]);
        __syncthreads();
    }
    float mx = red_s[0];
    __syncthreads();
    float p = (tid < NK) ? __expf(logit - mx) : 0.f;
    red_s[tid] = p;
    __syncthreads();
    for (int s = 128; s > 0; s >>= 1) {
        if (tid < s) red_s[tid] += red_s[tid + s];
        __syncthreads();
    }
    float inv_sum = 1.f / red_s[0];
    __syncthreads();
    red_s[tid] = p * inv_sum;
    __syncthreads();

    // ---- agg[h] = sum_k w[k] * nb[k][h]  (bf16 nb from LDS) ----
    if (tid < 64) {
        float a = 0.f;
        for (int k = 0; k < NK; ++k) {
            int byte = k * 128 + ((2 * tid) ^ ((k & 7) << 4));
            a += red_s[k] * bf2f(*reinterpret_cast<const short*>(
                     reinterpret_cast<const char*>(nb_s) + byte));
        }
        agg_s[tid] = a;
    }
    __syncthreads();

    // ---- heads projection + accumulate over l ----
    if (tid < 64) {
        const int n = tid >> 4, d = tid & 15;
        float hv = bh[tid];
        #pragma unroll 4
        for (int h = 0; h < 64; ++h)
            hv += agg_s[h] * Wh[n * (64 * 16) + h * 16 + d];
        atomicAdd(&acc_out[b * NHID + tid], hv);
    }
}

// ---- final head ----
__global__ __launch_bounds__(64) void final_kernel(
    const int* __restrict__ user_ids,
    const float* __restrict__ user_table,
    const float* __restrict__ acc,
    const float* __restrict__ Wf1, const float* __restrict__ bf1,
    const float* __restrict__ Wo,  const float* __restrict__ bo,
    float* __restrict__ out)
{
    const int b = blockIdx.x, h = threadIdx.x;
    __shared__ float ue[64], ag[64];
    const int uid = user_ids[b];
    ue[h] = user_table[(size_t)uid * 64 + h];
    ag[h] = acc[b * 64 + h] * (1.f / 50.f);
    __syncthreads();
    float z = bf1[h];
    #pragma unroll 4
    for (int i = 0; i < 64; ++i) z += ue[i] * Wf1[i * 64 + h];
    #pragma unroll 4
    for (int i = 0; i < 64; ++i) z += ag[i] * Wf1[(64 + i) * 64 + h];
    float t = fmaxf(z, 0.f) * Wo[h];
    #pragma unroll
    for (int off = 32; off > 0; off >>= 1) t += __shfl_down(t, off, 64);
    if (h == 0) out[b] = 1.f / (1.f + __expf(-(t + bo[0])));
}

extern "C" void kernel_launch(void* const* d_in, const int* in_sizes, int n_in,
                              void* d_out, int out_size, void* d_ws, size_t ws_size,
                              hipStream_t stream) {
    const int*   user_ids   = (const int*)d_in[0];
    const int*   history    = (const int*)d_in[2];
    const float* neighbor   = (const float*)d_in[3];
    const float* user_table = (const float*)d_in[4];
    const float* item_table = (const float*)d_in[5];
    const float* Wa  = (const float*)d_in[6];
    const float* ba  = (const float*)d_in[7];
    const float* W1  = (const float*)d_in[8];
    const float* b1  = (const float*)d_in[9];
    const float* W2  = (const float*)d_in[10];
    const float* b2  = (const float*)d_in[11];
    const float* W3  = (const float*)d_in[12];
    const float* b3  = (const float*)d_in[13];
    const float* Wh  = (const float*)d_in[14];
    const float* bh  = (const float*)d_in[15];
    const float* Wf1 = (const float*)d_in[16];
    const float* bf1 = (const float*)d_in[17];
    const float* Wo  = (const float*)d_in[18];
    const float* bo  = (const float*)d_in[19];

    float* acc = (float*)d_ws;                              // 64KB
    short* WaP = (short*)((char*)d_ws + 65536);             // 12288B
    short* W1P = (short*)((char*)d_ws + 77824);             // 9216B
    short* W2P = (short*)((char*)d_ws + 87040);             // 2048B

    hipMemsetAsync(acc, 0, NB * NHID * sizeof(float), stream);
    pack_kernel<<<1, 256, 0, stream>>>(Wa, W1, W2, WaP, W1P, W2P);
    edge_kernel<<<NB * NL, 256, 0, stream>>>(history, neighbor, item_table,
        Wa, ba, b1, b2, W3, b3, Wh, bh, WaP, W1P, W2P, acc);
    final_kernel<<<NB, 64, 0, stream>>>(user_ids, user_table, acc, Wf1, bf1, Wo, bo,
                                        (float*)d_out);
}

// Round 9
// 354.797 us; speedup vs baseline: 5.4585x; 1.1041x over previous
//
#include <hip/hip_runtime.h>
#include <hip/hip_bf16.h>
#include <math.h>

#define NB 256
#define NL 50
#define NK 100
#define NHID 64

typedef __attribute__((ext_vector_type(8))) short short8;   // 8 bf16 = 4 VGPR
typedef __attribute__((ext_vector_type(4))) short short4_t; // 4 bf16 = 8B
typedef __attribute__((ext_vector_type(4))) float floatx4;  // C/D frag

__device__ __forceinline__ short f2bf(float f) {
    __hip_bfloat16 h = __float2bfloat16(f);
    return *reinterpret_cast<short*>(&h);
}
__device__ __forceinline__ float bf2f(short s) {
    __hip_bfloat16 h = *reinterpret_cast<__hip_bfloat16*>(&s);
    return __bfloat162float(h);
}

// ---- pack weights into bf16 B-fragment order (lane-contiguous 16B) ----
// B-frag for 16x16x32: lane l holds B[k = kstep*32 + (l>>4)*8 + j][n0 + (l&15)], j=0..7
__global__ __launch_bounds__(256) void pack_kernel(
    const float* __restrict__ Wa, const float* __restrict__ W1,
    const float* __restrict__ W2,
    short* __restrict__ WaP, short* __restrict__ W1P, short* __restrict__ W2P)
{
    int t = threadIdx.x;
    for (int s = t; s < 12 * 64; s += 256) {        // Wa_bot [64,96]: 6 ntiles x 2 ksteps
        int l = s & 63, nt = s >> 6, n = nt >> 1, tk = nt & 1;
        int col = n * 16 + (l & 15);
        for (int j = 0; j < 8; ++j) {
            int k = tk * 32 + ((l >> 4) * 8) + j;
            WaP[s * 8 + j] = f2bf(Wa[(64 + k) * 96 + col]);
        }
    }
    for (int s = t; s < 9 * 64; s += 256) {         // W1 [96,48]: 3 ntiles x 3 ksteps
        int l = s & 63, nt = s >> 6, n = nt / 3, tk = nt % 3;
        int col = n * 16 + (l & 15);
        for (int j = 0; j < 8; ++j) {
            int k = tk * 32 + ((l >> 4) * 8) + j;
            W1P[s * 8 + j] = f2bf(W1[k * 48 + col]);
        }
    }
    for (int s = t; s < 2 * 64; s += 256) {         // W2 [48,16] pad K->64: 1 ntile x 2 ksteps
        int l = s & 63, tk = s >> 6;
        int col = l & 15;
        for (int j = 0; j < 8; ++j) {
            int k = tk * 32 + ((l >> 4) * 8) + j;
            W2P[s * 8 + j] = (k < 48) ? f2bf(W2[k * 16 + col]) : (short)0;
        }
    }
}

// ---- main fused kernel: one 256-thread block (4 waves) per (b,l) ----
__global__ __launch_bounds__(256) void edge_kernel(
    const int* __restrict__ history,
    const float* __restrict__ neighbor,
    const float* __restrict__ item_table,
    const float* __restrict__ Wa, const float* __restrict__ ba,
    const float* __restrict__ b1v, const float* __restrict__ b2,
    const float* __restrict__ W3, const float* __restrict__ b3,
    const float* __restrict__ Wh, const float* __restrict__ bh,
    const short* __restrict__ WaP, const short* __restrict__ W1P,
    const short* __restrict__ W2P,
    float* __restrict__ acc_out)
{
    const int bl  = blockIdx.x;
    const int b   = bl / NL;
    const int tid = threadIdx.x;

    // swizzle: byte ^= ((row&7)<<4) within rows (G4)
    __shared__ __align__(16) short nb_s[112 * 64];   // [112][64] bf16, 128B rows (100..111 junk)
    __shared__ __align__(16) char  z12_s[4][3072];   // per-wave union: z1 [16]x192B / z2 [16]x128B
    __shared__ float hist_s[64];
    __shared__ float base1_s[96];
    __shared__ float red_s[112];                     // logits -> softmax weights (in place)
    __shared__ float part_s[256];                    // 4-way partials (agg, then heads)
    __shared__ float agg_s[64];

    const int hid = history[bl];
    if (tid < 64) hist_s[tid] = item_table[(size_t)hid * NHID + tid];

    // stage neighbor tile -> swizzled bf16 LDS (float4-batched)
    const float4* nbg4 = reinterpret_cast<const float4*>(neighbor + (size_t)bl * (NK * NHID));
    for (int f4 = tid; f4 < NK * NHID / 4; f4 += 256) {
        int e = f4 >> 4, h4 = f4 & 15;
        float4 v = nbg4[f4];
        short4_t s;
        s[0] = f2bf(v.x); s[1] = f2bf(v.y); s[2] = f2bf(v.z); s[3] = f2bf(v.w);
        *reinterpret_cast<short4_t*>(reinterpret_cast<char*>(nb_s)
            + e * 128 + ((h4 * 8) ^ ((e & 7) << 4))) = s;
    }
    __syncthreads();

    // base1[j] = ba[j] + hist . Wa_top[:,j]  (fp32, shared across all 100 edges)
    if (tid < 96) {
        float a = ba[tid];
        #pragma unroll 4
        for (int i = 0; i < 64; ++i) a += hist_s[i] * Wa[i * 96 + tid];
        base1_s[tid] = a;
    }
    __syncthreads();

    const int wv = tid >> 6, ln = tid & 63;
    const int lr = ln & 15;          // A-row / C-col within tile
    const int lg = ln >> 4;          // k-group / C-row-group
    char* zp = z12_s[wv];

    const short8* WaPv = reinterpret_cast<const short8*>(WaP);
    const short8* W1Pv = reinterpret_cast<const short8*>(W1P);
    const short8* W2Pv = reinterpret_cast<const short8*>(W2P);
    const float b2c = b2[lr], w3c = W3[lr], b3s = b3[0];
    const int lsw = (lr & 7) << 4;

    // each wave owns M-tiles {wv, wv+4}; rows 100..111 junk -> masked at softmax
    for (int mi = wv; mi < 7; mi += 4) {
        const int er = mi * 16 + lr;
        const char* nbp = reinterpret_cast<const char*>(nb_s) + er * 128;
        const int esw = (er & 7) << 4;
        short8 a0 = *reinterpret_cast<const short8*>(nbp + ((lg * 16 +  0) ^ esw));
        short8 a1 = *reinterpret_cast<const short8*>(nbp + ((lg * 16 + 64) ^ esw));

        // ---- L1: [16,64] x [64,96] -> relu(+base1) -> z1 (LDS, 192B rows) ----
        #pragma unroll
        for (int n = 0; n < 6; ++n) {
            floatx4 acc = {0.f, 0.f, 0.f, 0.f};
            acc = __builtin_amdgcn_mfma_f32_16x16x32_bf16(a0, WaPv[(n * 2 + 0) * 64 + ln], acc, 0, 0, 0);
            acc = __builtin_amdgcn_mfma_f32_16x16x32_bf16(a1, WaPv[(n * 2 + 1) * 64 + ln], acc, 0, 0, 0);
            float base = base1_s[n * 16 + lr];
            #pragma unroll
            for (int i = 0; i < 4; ++i) {
                int r = lg * 4 + i;
                float z = fmaxf(acc[i] + base, 0.f);
                *reinterpret_cast<short*>(zp + r * 192 + ((2 * (n * 16 + lr)) ^ ((r & 7) << 4))) = f2bf(z);
            }
        }

        // ---- L2: [16,96] x [96,48] -> relu(+b1) -> z2 (LDS, 128B rows, overlays z1) ----
        // all of z1 is consumed into registers (za0..za2) BEFORE any z2 write
        short8 za0 = *reinterpret_cast<const short8*>(zp + lr * 192 + ((  0 + lg * 16) ^ lsw));
        short8 za1 = *reinterpret_cast<const short8*>(zp + lr * 192 + (( 64 + lg * 16) ^ lsw));
        short8 za2 = *reinterpret_cast<const short8*>(zp + lr * 192 + ((128 + lg * 16) ^ lsw));
        #pragma unroll
        for (int n = 0; n < 3; ++n) {
            floatx4 acc = {0.f, 0.f, 0.f, 0.f};
            acc = __builtin_amdgcn_mfma_f32_16x16x32_bf16(za0, W1Pv[(n * 3 + 0) * 64 + ln], acc, 0, 0, 0);
            acc = __builtin_amdgcn_mfma_f32_16x16x32_bf16(za1, W1Pv[(n * 3 + 1) * 64 + ln], acc, 0, 0, 0);
            acc = __builtin_amdgcn_mfma_f32_16x16x32_bf16(za2, W1Pv[(n * 3 + 2) * 64 + ln], acc, 0, 0, 0);
            float bias = b1v[n * 16 + lr];
            #pragma unroll
            for (int i = 0; i < 4; ++i) {
                int r = lg * 4 + i;
                float z = fmaxf(acc[i] + bias, 0.f);
                *reinterpret_cast<short*>(zp + r * 128 + ((2 * (n * 16 + lr)) ^ ((r & 7) << 4))) = f2bf(z);
            }
        }

        // ---- L3: [16,48] x [48,16(pad64)] -> relu(+b2) . W3 -> logits ----
        // K=48: zb1 upper half (k>=48 <=> lg>=2) zeroed in registers, no LDS pad
        short8 zb0 = *reinterpret_cast<const short8*>(zp + lr * 128 + ((lg * 16) ^ lsw));
        short8 zb1 = short8{0, 0, 0, 0, 0, 0, 0, 0};
        if (lg < 2)
            zb1 = *reinterpret_cast<const short8*>(zp + lr * 128 + ((64 + lg * 16) ^ lsw));
        floatx4 acc3 = {0.f, 0.f, 0.f, 0.f};
        acc3 = __builtin_amdgcn_mfma_f32_16x16x32_bf16(zb0, W2Pv[ln], acc3, 0, 0, 0);
        acc3 = __builtin_amdgcn_mfma_f32_16x16x32_bf16(zb1, W2Pv[64 + ln], acc3, 0, 0, 0);
        #pragma unroll
        for (int i = 0; i < 4; ++i) {
            float tL = fmaxf(acc3[i] + b2c, 0.f) * w3c;
            tL += __shfl_xor(tL, 1, 64);
            tL += __shfl_xor(tL, 2, 64);
            tL += __shfl_xor(tL, 4, 64);
            tL += __shfl_xor(tL, 8, 64);
            if (lr == 0) red_s[mi * 16 + lg * 4 + i] = tL + b3s;
        }
    }
    __syncthreads();

    // ---- softmax over 100 edges: wave 0, in-register shuffle ----
    if (tid < 64) {
        float l0 = red_s[tid];                                  // tid < 100 always
        float l1 = (tid < NK - 64) ? red_s[64 + tid] : -1e30f;
        float m = fmaxf(l0, l1);
        #pragma unroll
        for (int off = 32; off > 0; off >>= 1) m = fmaxf(m, __shfl_xor(m, off, 64));
        float p0 = __expf(l0 - m);
        float p1 = (tid < NK - 64) ? __expf(l1 - m) : 0.f;
        float s = p0 + p1;
        #pragma unroll
        for (int off = 32; off > 0; off >>= 1) s += __shfl_xor(s, off, 64);
        float inv = 1.f / s;
        red_s[tid] = p0 * inv;
        if (tid < NK - 64) red_s[64 + tid] = p1 * inv;
    }
    __syncthreads();

    // ---- agg[h] = sum_k w[k]*nb[k][h] : 4-way K-split across waves ----
    {
        int q = tid >> 6, h = tid & 63;
        float a = 0.f;
        #pragma unroll
        for (int kk = 0; kk < 25; ++kk) {
            int k = q * 25 + kk;
            a += red_s[k] * bf2f(*reinterpret_cast<const short*>(
                     reinterpret_cast<const char*>(nb_s) + k * 128 + ((2 * h) ^ ((k & 7) << 4))));
        }
        part_s[tid] = a;
    }
    __syncthreads();
    if (tid < 64)
        agg_s[tid] = part_s[tid] + part_s[64 + tid] + part_s[128 + tid] + part_s[192 + tid];
    __syncthreads();

    // ---- heads: 4-way H-split across waves ----
    {
        int q = tid >> 6, t = tid & 63, n = t >> 4, d = t & 15;
        float hv = 0.f;
        #pragma unroll
        for (int hh = 0; hh < 16; ++hh) {
            int h = q * 16 + hh;
            hv += agg_s[h] * Wh[n * (64 * 16) + h * 16 + d];
        }
        part_s[tid] = hv;
    }
    __syncthreads();
    if (tid < 64)
        atomicAdd(&acc_out[b * NHID + tid],
                  bh[tid] + part_s[tid] + part_s[64 + tid] + part_s[128 + tid] + part_s[192 + tid]);
}

// ---- final head ----
__global__ __launch_bounds__(64) void final_kernel(
    const int* __restrict__ user_ids,
    const float* __restrict__ user_table,
    const float* __restrict__ acc,
    const float* __restrict__ Wf1, const float* __restrict__ bf1,
    const float* __restrict__ Wo,  const float* __restrict__ bo,
    float* __restrict__ out)
{
    const int b = blockIdx.x, h = threadIdx.x;
    __shared__ float ue[64], ag[64];
    const int uid = user_ids[b];
    ue[h] = user_table[(size_t)uid * 64 + h];
    ag[h] = acc[b * 64 + h] * (1.f / 50.f);
    __syncthreads();
    float z = bf1[h];
    #pragma unroll 4
    for (int i = 0; i < 64; ++i) z += ue[i] * Wf1[i * 64 + h];
    #pragma unroll 4
    for (int i = 0; i < 64; ++i) z += ag[i] * Wf1[(64 + i) * 64 + h];
    float t = fmaxf(z, 0.f) * Wo[h];
    #pragma unroll
    for (int off = 32; off > 0; off >>= 1) t += __shfl_down(t, off, 64);
    if (h == 0) out[b] = 1.f / (1.f + __expf(-(t + bo[0])));
}

extern "C" void kernel_launch(void* const* d_in, const int* in_sizes, int n_in,
                              void* d_out, int out_size, void* d_ws, size_t ws_size,
                              hipStream_t stream) {
    const int*   user_ids   = (const int*)d_in[0];
    const int*   history    = (const int*)d_in[2];
    const float* neighbor   = (const float*)d_in[3];
    const float* user_table = (const float*)d_in[4];
    const float* item_table = (const float*)d_in[5];
    const float* Wa  = (const float*)d_in[6];
    const float* ba  = (const float*)d_in[7];
    const float* W1  = (const float*)d_in[8];
    const float* b1  = (const float*)d_in[9];
    const float* W2  = (const float*)d_in[10];
    const float* b2  = (const float*)d_in[11];
    const float* W3  = (const float*)d_in[12];
    const float* b3  = (const float*)d_in[13];
    const float* Wh  = (const float*)d_in[14];
    const float* bh  = (const float*)d_in[15];
    const float* Wf1 = (const float*)d_in[16];
    const float* bf1 = (const float*)d_in[17];
    const float* Wo  = (const float*)d_in[18];
    const float* bo  = (const float*)d_in[19];

    float* acc = (float*)d_ws;                              // 64KB
    short* WaP = (short*)((char*)d_ws + 65536);             // 12288B
    short* W1P = (short*)((char*)d_ws + 77824);             // 9216B
    short* W2P = (short*)((char*)d_ws + 87040);             // 2048B

    hipMemsetAsync(acc, 0, NB * NHID * sizeof(float), stream);
    pack_kernel<<<1, 256, 0, stream>>>(Wa, W1, W2, WaP, W1P, W2P);
    edge_kernel<<<NB * NL, 256, 0, stream>>>(history, neighbor, item_table,
        Wa, ba, b1, b2, W3, b3, Wh, bh, WaP, W1P, W2P, acc);
    final_kernel<<<NB, 64, 0, stream>>>(user_ids, user_table, acc, Wf1, bf1, Wo, bo,
                                        (float*)d_out);
}